// Round 4
// baseline (203.992 us; speedup 1.0000x reference)
//
#include <hip/hip_runtime.h>
#include <math.h>

#define KPOT 5
#define ROWS_PER_TILE 1024        // per block-iteration (4 waves x 256 rows)
#define GRID_BLOCKS 1024          // persistent: 4 blocks/CU (LDS-limited)

// Barrier-free pipelined design:
//  - Each wave owns 256 rows/tile and a private 5 KB x2 LDS slice for gumbel.
//    Writer == reader => NO __syncthreads anywhere in the main loop, so no
//    vmcnt(0) drain; loads for tile i+1 stay in flight across compute of tile i.
//  - All global accesses are lane-contiguous float4 (16 B/lane, 1 KB/instr).
//  - LDS read layout matches R3's measured-zero-conflict pattern (10t dwords).
__global__ __launch_bounds__(256, 4) void lightsb_kernel(
    const float* __restrict__ x,
    const float* __restrict__ r,
    const float* __restrict__ log_S,
    const float* __restrict__ log_alpha,
    const float* __restrict__ gumbel,
    const float* __restrict__ noise,
    float* __restrict__ out,
    int n_rows)
{
    __shared__ float4 gsh[2 * 4 * 320];   // 2 bufs x 4 waves x 320 float4 = 40 KB

    const int t = threadIdx.x;
    const int w = t >> 6;                 // wave id 0..3
    const int L = t & 63;                 // lane

    const long long nTiles = n_rows / ROWS_PER_TILE;

    // ---- prologue: issue tile0 loads first, params overlap the latency ----
    long long tile = blockIdx.x;
    float4 gv0[5], xv0[2], nv0[2];
    if (tile < nTiles) {
        const float4* g4 = reinterpret_cast<const float4*>(gumbel) + tile * 1280 + w * 320;
        const float4* x4 = reinterpret_cast<const float4*>(x)      + tile * 512  + w * 128;
        const float4* n4 = reinterpret_cast<const float4*>(noise)  + tile * 512  + w * 128;
#pragma unroll
        for (int j = 0; j < 5; ++j) gv0[j] = g4[j * 64 + L];
        xv0[0] = x4[L];      xv0[1] = x4[64 + L];
        nv0[0] = n4[L];      nv0[1] = n4[64 + L];
    }

    float S0[KPOT], S1[KPOT], r0[KPOT], r1[KPOT], la[KPOT], q0[KPOT], q1[KPOT];
#pragma unroll
    for (int k = 0; k < KPOT; ++k) {
        float s0 = expf(log_S[2 * k + 0]);
        float s1 = expf(log_S[2 * k + 1]);
        S0[k] = s0;  S1[k] = s1;
        r0[k] = r[2 * k + 0];  r1[k] = r[2 * k + 1];
        la[k] = log_alpha[k];
        q0[k] = sqrtf(s0);  q1[k] = sqrtf(s1);   // EPS = 1.0
    }

    int buf = 0;
    if (tile < nTiles) {
        float4* dst = gsh + w * 320;              // buf 0
#pragma unroll
        for (int j = 0; j < 5; ++j) dst[j * 64 + L] = gv0[j];
    }

    // ---- main pipelined loop (no barriers; wave-private LDS) ----
    while (tile < nTiles) {
        const long long ntile = tile + GRID_BLOCKS;
        const bool more = (ntile < nTiles);

        float4 gv1[5], xv1[2], nv1[2];
        if (more) {                               // prefetch tile i+1 (9 loads in flight)
            const float4* g4 = reinterpret_cast<const float4*>(gumbel) + ntile * 1280 + w * 320;
#pragma unroll
            for (int j = 0; j < 5; ++j) gv1[j] = g4[j * 64 + L];
            const float4* x4 = reinterpret_cast<const float4*>(x)     + ntile * 512 + w * 128;
            const float4* n4 = reinterpret_cast<const float4*>(noise) + ntile * 512 + w * 128;
            xv1[0] = x4[L];      xv1[1] = x4[64 + L];
            nv1[0] = n4[L];      nv1[1] = n4[64 + L];
        }

        // compute current tile from LDS[buf] + registers
        const float* gbase = reinterpret_cast<const float*>(gsh + buf * 1280 + w * 320);
        float4* o4 = reinterpret_cast<float4*>(out) + tile * 512 + w * 128;

#pragma unroll
        for (int h = 0; h < 2; ++h) {             // two float4s = rows {h*128+2L, +1}
            const float4 xv = xv0[h];
            const float4 nv = nv0[h];
            const float* g = gbase + h * 640 + 10 * L;   // 10 consecutive floats
            float ov[4];
#pragma unroll
            for (int hh = 0; hh < 2; ++hh) {
                const float xx0 = (hh == 0) ? xv.x : xv.z;
                const float xx1 = (hh == 0) ? xv.y : xv.w;
                const float nn0 = (hh == 0) ? nv.x : nv.z;
                const float nn1 = (hh == 0) ? nv.y : nv.w;
                const float* gg = g + hh * KPOT;

                const float u0 = 0.5f * xx0 * xx0;
                const float u1 = 0.5f * xx1 * xx1;

                float best = fmaf(S0[0], u0, fmaf(S1[0], u1,
                             fmaf(r0[0], xx0, fmaf(r1[0], xx1, la[0] + gg[0]))));
                float bS0 = S0[0], bS1 = S1[0];
                float br0 = r0[0], br1 = r1[0];
                float bq0 = q0[0], bq1 = q1[0];
#pragma unroll
                for (int k = 1; k < KPOT; ++k) {
                    float s = fmaf(S0[k], u0, fmaf(S1[k], u1,
                              fmaf(r0[k], xx0, fmaf(r1[k], xx1, la[k] + gg[k]))));
                    bool c = s > best;    // strict > keeps first max (jnp.argmax)
                    best = c ? s : best;
                    bS0 = c ? S0[k] : bS0;
                    bS1 = c ? S1[k] : bS1;
                    br0 = c ? r0[k] : br0;
                    br1 = c ? r1[k] : br1;
                    bq0 = c ? q0[k] : bq0;
                    bq1 = c ? q1[k] : bq1;
                }
                ov[2 * hh + 0] = fmaf(bS0, xx0, fmaf(bq0, nn0, br0));
                ov[2 * hh + 1] = fmaf(bS1, xx1, fmaf(bq1, nn1, br1));
            }
            o4[h * 64 + L] = make_float4(ov[0], ov[1], ov[2], ov[3]);
        }

        if (more) {
            // stage next tile's gumbel into the other buffer (same wave reads it
            // next iteration -> program order within the wave guarantees safety)
            float4* dst = gsh + (buf ^ 1) * 1280 + w * 320;
#pragma unroll
            for (int j = 0; j < 5; ++j) dst[j * 64 + L] = gv1[j];
            xv0[0] = xv1[0];  xv0[1] = xv1[1];
            nv0[0] = nv1[0];  nv0[1] = nv1[1];
        }
        buf ^= 1;
        tile = ntile;
    }

    // ---- generic scalar tail (n_rows % 1024 != 0; zero iterations here) ----
    for (long long row = nTiles * ROWS_PER_TILE + (long long)blockIdx.x * 256 + t;
         row < n_rows;
         row += (long long)GRID_BLOCKS * 256) {
        float x0 = x[row * 2 + 0];
        float x1 = x[row * 2 + 1];
        float u0 = 0.5f * x0 * x0;
        float u1 = 0.5f * x1 * x1;
        float best = fmaf(S0[0], u0, fmaf(S1[0], u1,
                     fmaf(r0[0], x0, fmaf(r1[0], x1, la[0] + gumbel[row * KPOT + 0]))));
        int bidx = 0;
#pragma unroll
        for (int k = 1; k < KPOT; ++k) {
            float s = fmaf(S0[k], u0, fmaf(S1[k], u1,
                      fmaf(r0[k], x0, fmaf(r1[k], x1, la[k] + gumbel[row * KPOT + k]))));
            if (s > best) { best = s; bidx = k; }
        }
        float n0 = noise[row * 2 + 0];
        float n1 = noise[row * 2 + 1];
        out[row * 2 + 0] = fmaf(S0[bidx], x0, fmaf(q0[bidx], n0, r0[bidx]));
        out[row * 2 + 1] = fmaf(S1[bidx], x1, fmaf(q1[bidx], n1, r1[bidx]));
    }
}

extern "C" void kernel_launch(void* const* d_in, const int* in_sizes, int n_in,
                              void* d_out, int out_size, void* d_ws, size_t ws_size,
                              hipStream_t stream) {
    const float* x         = (const float*)d_in[0];
    const float* r         = (const float*)d_in[1];
    const float* log_S     = (const float*)d_in[2];
    const float* log_alpha = (const float*)d_in[3];
    const float* gumbel    = (const float*)d_in[4];
    const float* noise     = (const float*)d_in[5];
    float* out = (float*)d_out;

    const int n_rows = in_sizes[0] / 2;   // DIM = 2

    lightsb_kernel<<<GRID_BLOCKS, 256, 0, stream>>>(x, r, log_S, log_alpha,
                                                    gumbel, noise, out, n_rows);
}

// Round 5
// 189.841 us; speedup vs baseline: 1.0745x; 1.0745x over previous
//
#include <hip/hip_runtime.h>
#include <math.h>

#define KPOT 5
#define ROWS_PER_BLOCK 1024      // 4 waves x 256 rows

// One-shot blocks, per-wave-PRIVATE LDS staging => NO __syncthreads anywhere.
// Load order: gumbel(5) -> x(2) -> noise(2). vmcnt is FIFO, so:
//   ds_write(gumbel)  waits vmcnt(4)   (x, noise still in flight)
//   logit compute     waits vmcnt(2)   (noise still in flight)
//   epilogue          waits vmcnt(0)
// No monolithic vmcnt(0)+s_barrier drain like R3. 20 KB LDS -> ~8 blocks/CU.
__global__ __launch_bounds__(256, 4) void lightsb_kernel(
    const float* __restrict__ x,
    const float* __restrict__ r,
    const float* __restrict__ log_S,
    const float* __restrict__ log_alpha,
    const float* __restrict__ gumbel,
    const float* __restrict__ noise,
    float* __restrict__ out,
    int n_rows)
{
    __shared__ float4 gsh[4 * 320];          // 4 waves x 320 float4 = 20 KB

    const int t = threadIdx.x;
    const int w = t >> 6;                    // wave id 0..3
    const int L = t & 63;                    // lane id

    const long long blockRow0 = (long long)blockIdx.x * ROWS_PER_BLOCK;

    float S0[KPOT], S1[KPOT], r0[KPOT], r1[KPOT], la[KPOT], q0[KPOT], q1[KPOT];

    if (blockRow0 + ROWS_PER_BLOCK <= n_rows) {
        // wave w owns rows [blockRow0 + 256w, +256)
        // ---- issue loads: gumbel first, then x, then noise (all lane-contiguous float4) ----
        const float4* g4 = reinterpret_cast<const float4*>(gumbel)
                           + blockRow0 * KPOT / 4 + w * 320;
        float4 gv[5];
#pragma unroll
        for (int j = 0; j < 5; ++j) gv[j] = g4[j * 64 + L];

        const float4* x4 = reinterpret_cast<const float4*>(x) + blockRow0 / 2 + w * 128;
        float4 xa = x4[L];                   // rows 2L, 2L+1   (within wave window)
        float4 xb = x4[64 + L];              // rows 128+2L, 128+2L+1

        const float4* n4 = reinterpret_cast<const float4*>(noise) + blockRow0 / 2 + w * 128;
        float4 na = n4[L];
        float4 nb = n4[64 + L];

        // ---- param setup overlaps load latency (uniform scalar loads + v_exp) ----
#pragma unroll
        for (int k = 0; k < KPOT; ++k) {
            float s0 = expf(log_S[2 * k + 0]);
            float s1 = expf(log_S[2 * k + 1]);
            S0[k] = s0;  S1[k] = s1;
            r0[k] = r[2 * k + 0];  r1[k] = r[2 * k + 1];
            la[k] = log_alpha[k];
            q0[k] = sqrtf(s0);  q1[k] = sqrtf(s1);   // EPS = 1.0
        }

        // ---- stage this wave's gumbel slice into its private LDS slice ----
        float4* dst = gsh + w * 320;
#pragma unroll
        for (int j = 0; j < 5; ++j) dst[j * 64 + L] = gv[j];
        // writer == reader (same wave): program order + compiler lgkmcnt suffice.

        const float* gf = reinterpret_cast<const float*>(gsh + w * 320);
        float4* o4 = reinterpret_cast<float4*>(out) + blockRow0 / 2 + w * 128;

#pragma unroll
        for (int h = 0; h < 2; ++h) {        // h=0: rows 2L,2L+1 ; h=1: rows 128+2L,+1
            const float4 xv = (h == 0) ? xa : xb;
            const float4 nv = (h == 0) ? na : nb;
            const float* g0 = gf + h * 640 + 10 * L;   // 10 consecutive dwords
            float ov[4];
#pragma unroll
            for (int hh = 0; hh < 2; ++hh) {
                const float xx0 = (hh == 0) ? xv.x : xv.z;
                const float xx1 = (hh == 0) ? xv.y : xv.w;
                const float nn0 = (hh == 0) ? nv.x : nv.z;
                const float nn1 = (hh == 0) ? nv.y : nv.w;
                const float* g = g0 + hh * KPOT;

                const float u0 = 0.5f * xx0 * xx0;
                const float u1 = 0.5f * xx1 * xx1;

                float best = fmaf(S0[0], u0, fmaf(S1[0], u1,
                             fmaf(r0[0], xx0, fmaf(r1[0], xx1, la[0] + g[0]))));
                float bS0 = S0[0], bS1 = S1[0];
                float br0 = r0[0], br1 = r1[0];
                float bq0 = q0[0], bq1 = q1[0];
#pragma unroll
                for (int k = 1; k < KPOT; ++k) {
                    float s = fmaf(S0[k], u0, fmaf(S1[k], u1,
                              fmaf(r0[k], xx0, fmaf(r1[k], xx1, la[k] + g[k]))));
                    bool c = s > best;       // strict > keeps first max (jnp.argmax)
                    best = c ? s : best;
                    bS0 = c ? S0[k] : bS0;
                    bS1 = c ? S1[k] : bS1;
                    br0 = c ? r0[k] : br0;
                    br1 = c ? r1[k] : br1;
                    bq0 = c ? q0[k] : bq0;
                    bq1 = c ? q1[k] : bq1;
                }
                ov[2 * hh + 0] = fmaf(bS0, xx0, fmaf(bq0, nn0, br0));
                ov[2 * hh + 1] = fmaf(bS1, xx1, fmaf(bq1, nn1, br1));
            }
            o4[h * 64 + L] = make_float4(ov[0], ov[1], ov[2], ov[3]);
        }
    } else {
        // ---- scalar fallback for a partial last block ----
#pragma unroll
        for (int k = 0; k < KPOT; ++k) {
            float s0 = expf(log_S[2 * k + 0]);
            float s1 = expf(log_S[2 * k + 1]);
            S0[k] = s0;  S1[k] = s1;
            r0[k] = r[2 * k + 0];  r1[k] = r[2 * k + 1];
            la[k] = log_alpha[k];
            q0[k] = sqrtf(s0);  q1[k] = sqrtf(s1);
        }
        for (long long row = blockRow0 + t; row < n_rows; row += 256) {
            float x0 = x[row * 2 + 0];
            float x1 = x[row * 2 + 1];
            float u0 = 0.5f * x0 * x0;
            float u1 = 0.5f * x1 * x1;
            float best = fmaf(S0[0], u0, fmaf(S1[0], u1,
                         fmaf(r0[0], x0, fmaf(r1[0], x1, la[0] + gumbel[row * KPOT + 0]))));
            int bidx = 0;
#pragma unroll
            for (int k = 1; k < KPOT; ++k) {
                float s = fmaf(S0[k], u0, fmaf(S1[k], u1,
                          fmaf(r0[k], x0, fmaf(r1[k], x1, la[k] + gumbel[row * KPOT + k]))));
                if (s > best) { best = s; bidx = k; }
            }
            float n0 = noise[row * 2 + 0];
            float n1 = noise[row * 2 + 1];
            out[row * 2 + 0] = fmaf(S0[bidx], x0, fmaf(q0[bidx], n0, r0[bidx]));
            out[row * 2 + 1] = fmaf(S1[bidx], x1, fmaf(q1[bidx], n1, r1[bidx]));
        }
    }
}

extern "C" void kernel_launch(void* const* d_in, const int* in_sizes, int n_in,
                              void* d_out, int out_size, void* d_ws, size_t ws_size,
                              hipStream_t stream) {
    const float* x         = (const float*)d_in[0];
    const float* r         = (const float*)d_in[1];
    const float* log_S     = (const float*)d_in[2];
    const float* log_alpha = (const float*)d_in[3];
    const float* gumbel    = (const float*)d_in[4];
    const float* noise     = (const float*)d_in[5];
    float* out = (float*)d_out;

    const int n_rows = in_sizes[0] / 2;                      // DIM = 2
    const int grid = (n_rows + ROWS_PER_BLOCK - 1) / ROWS_PER_BLOCK;

    lightsb_kernel<<<grid, 256, 0, stream>>>(x, r, log_S, log_alpha,
                                             gumbel, noise, out, n_rows);
}

// Round 6
// 188.973 us; speedup vs baseline: 1.0795x; 1.0046x over previous
//
#include <hip/hip_runtime.h>
#include <math.h>

#define KPOT 5
#define ROWS_PER_BLOCK 1024      // 4 waves x 256 rows
#define AS1 __attribute__((address_space(1)))
#define AS3 __attribute__((address_space(3)))

// One-shot blocks, wave-private LDS, NO barriers, and — key change —
// gumbel staged via async global_load_lds (16 B/lane): zero landing VGPRs,
// so all 9 memory ops per wave are in flight simultaneously (~9 KB/wave).
// x/noise stay in registers (16 VGPRs). One per-wave s_waitcnt vmcnt(0)
// (imm 0xF70: expcnt/lgkmcnt masked) replaces the block-wide barrier drain.
__global__ __launch_bounds__(256) void lightsb_kernel(
    const float* __restrict__ x,
    const float* __restrict__ r,
    const float* __restrict__ log_S,
    const float* __restrict__ log_alpha,
    const float* __restrict__ gumbel,
    const float* __restrict__ noise,
    float* __restrict__ out,
    int n_rows)
{
    __shared__ float4 gsh[4 * 320];          // 4 waves x 320 float4 = 20 KB

    const int t = threadIdx.x;
    const int w = t >> 6;                    // wave id 0..3 (uniform per wave)
    const int L = t & 63;                    // lane id

    const long long blockRow0 = (long long)blockIdx.x * ROWS_PER_BLOCK;

    float S0[KPOT], S1[KPOT], r0[KPOT], r1[KPOT], la[KPOT], q0[KPOT], q1[KPOT];

    if (blockRow0 + ROWS_PER_BLOCK <= n_rows) {
        // ---- async gumbel -> LDS (5 x 16 B/lane, no VGPR landing) ----
        const float4* g4 = reinterpret_cast<const float4*>(gumbel)
                           + blockRow0 * KPOT / 4 + w * 320;
        float4* dst = gsh + w * 320;         // wave-uniform base; HW adds lane*16
#pragma unroll
        for (int j = 0; j < 5; ++j) {
            __builtin_amdgcn_global_load_lds(
                (const AS1 void*)(g4 + j * 64 + L),
                (AS3 void*)(dst + j * 64),
                16, 0, 0);
        }

        // ---- x / noise into registers (4 x float4, lane-contiguous) ----
        const float4* x4 = reinterpret_cast<const float4*>(x) + blockRow0 / 2 + w * 128;
        float4 xa = x4[L];                   // rows 2L, 2L+1 (wave window)
        float4 xb = x4[64 + L];              // rows 128+2L, 128+2L+1
        const float4* n4 = reinterpret_cast<const float4*>(noise) + blockRow0 / 2 + w * 128;
        float4 na = n4[L];
        float4 nb = n4[64 + L];

        // ---- param setup overlaps the 9 in-flight loads ----
#pragma unroll
        for (int k = 0; k < KPOT; ++k) {
            float s0 = expf(log_S[2 * k + 0]);
            float s1 = expf(log_S[2 * k + 1]);
            S0[k] = s0;  S1[k] = s1;
            r0[k] = r[2 * k + 0];  r1[k] = r[2 * k + 1];
            la[k] = log_alpha[k];
            q0[k] = sqrtf(s0);  q1[k] = sqrtf(s1);   // EPS = 1.0
        }

        // ---- per-wave drain of our own loads (NOT a barrier) ----
        // imm 0xF70 = vmcnt(0), expcnt(7)=nowait, lgkmcnt(15)=nowait
        __builtin_amdgcn_s_waitcnt(0x0F70);
        __builtin_amdgcn_sched_barrier(0);   // keep LDS reads below the wait

        const float* gf = reinterpret_cast<const float*>(gsh + w * 320);
        float4* o4 = reinterpret_cast<float4*>(out) + blockRow0 / 2 + w * 128;

#pragma unroll
        for (int h = 0; h < 2; ++h) {        // h=0: rows 2L,2L+1 ; h=1: rows 128+2L,+1
            const float4 xv = (h == 0) ? xa : xb;
            const float4 nv = (h == 0) ? na : nb;
            const float* g0 = gf + h * 640 + 10 * L;   // 10 consecutive dwords
            float ov[4];
#pragma unroll
            for (int hh = 0; hh < 2; ++hh) {
                const float xx0 = (hh == 0) ? xv.x : xv.z;
                const float xx1 = (hh == 0) ? xv.y : xv.w;
                const float nn0 = (hh == 0) ? nv.x : nv.z;
                const float nn1 = (hh == 0) ? nv.y : nv.w;
                const float* g = g0 + hh * KPOT;

                const float u0 = 0.5f * xx0 * xx0;
                const float u1 = 0.5f * xx1 * xx1;

                float best = fmaf(S0[0], u0, fmaf(S1[0], u1,
                             fmaf(r0[0], xx0, fmaf(r1[0], xx1, la[0] + g[0]))));
                float bS0 = S0[0], bS1 = S1[0];
                float br0 = r0[0], br1 = r1[0];
                float bq0 = q0[0], bq1 = q1[0];
#pragma unroll
                for (int k = 1; k < KPOT; ++k) {
                    float s = fmaf(S0[k], u0, fmaf(S1[k], u1,
                              fmaf(r0[k], xx0, fmaf(r1[k], xx1, la[k] + g[k]))));
                    bool c = s > best;       // strict > keeps first max (jnp.argmax)
                    best = c ? s : best;
                    bS0 = c ? S0[k] : bS0;
                    bS1 = c ? S1[k] : bS1;
                    br0 = c ? r0[k] : br0;
                    br1 = c ? r1[k] : br1;
                    bq0 = c ? q0[k] : bq0;
                    bq1 = c ? q1[k] : bq1;
                }
                ov[2 * hh + 0] = fmaf(bS0, xx0, fmaf(bq0, nn0, br0));
                ov[2 * hh + 1] = fmaf(bS1, xx1, fmaf(bq1, nn1, br1));
            }
            o4[h * 64 + L] = make_float4(ov[0], ov[1], ov[2], ov[3]);
        }
    } else {
        // ---- scalar fallback for a partial last block ----
#pragma unroll
        for (int k = 0; k < KPOT; ++k) {
            float s0 = expf(log_S[2 * k + 0]);
            float s1 = expf(log_S[2 * k + 1]);
            S0[k] = s0;  S1[k] = s1;
            r0[k] = r[2 * k + 0];  r1[k] = r[2 * k + 1];
            la[k] = log_alpha[k];
            q0[k] = sqrtf(s0);  q1[k] = sqrtf(s1);
        }
        for (long long row = blockRow0 + t; row < n_rows; row += 256) {
            float x0 = x[row * 2 + 0];
            float x1 = x[row * 2 + 1];
            float u0 = 0.5f * x0 * x0;
            float u1 = 0.5f * x1 * x1;
            float best = fmaf(S0[0], u0, fmaf(S1[0], u1,
                         fmaf(r0[0], x0, fmaf(r1[0], x1, la[0] + gumbel[row * KPOT + 0]))));
            int bidx = 0;
#pragma unroll
            for (int k = 1; k < KPOT; ++k) {
                float s = fmaf(S0[k], u0, fmaf(S1[k], u1,
                          fmaf(r0[k], x0, fmaf(r1[k], x1, la[k] + gumbel[row * KPOT + k]))));
                if (s > best) { best = s; bidx = k; }
            }
            float n0 = noise[row * 2 + 0];
            float n1 = noise[row * 2 + 1];
            out[row * 2 + 0] = fmaf(S0[bidx], x0, fmaf(q0[bidx], n0, r0[bidx]));
            out[row * 2 + 1] = fmaf(S1[bidx], x1, fmaf(q1[bidx], n1, r1[bidx]));
        }
    }
}

extern "C" void kernel_launch(void* const* d_in, const int* in_sizes, int n_in,
                              void* d_out, int out_size, void* d_ws, size_t ws_size,
                              hipStream_t stream) {
    const float* x         = (const float*)d_in[0];
    const float* r         = (const float*)d_in[1];
    const float* log_S     = (const float*)d_in[2];
    const float* log_alpha = (const float*)d_in[3];
    const float* gumbel    = (const float*)d_in[4];
    const float* noise     = (const float*)d_in[5];
    float* out = (float*)d_out;

    const int n_rows = in_sizes[0] / 2;                      // DIM = 2
    const int grid = (n_rows + ROWS_PER_BLOCK - 1) / ROWS_PER_BLOCK;

    lightsb_kernel<<<grid, 256, 0, stream>>>(x, r, log_S, log_alpha,
                                             gumbel, noise, out, n_rows);
}